// Round 1
// baseline (641.765 us; speedup 1.0000x reference)
//
#include <hip/hip_runtime.h>
#include <stdint.h>
#include <stddef.h>

// ---------- types ----------
typedef __attribute__((ext_vector_type(4))) float f32x4;
typedef __attribute__((ext_vector_type(4))) int   i32x4;
typedef __attribute__((ext_vector_type(8))) short s16x8;
typedef __attribute__((ext_vector_type(4))) short s16x4;
typedef __attribute__((ext_vector_type(8))) __bf16 bf16x8;

#define AS3 __attribute__((address_space(3)))
#define AS1 __attribute__((address_space(1)))

__device__ inline void gload16(const void* g, void* l) {
  // async global->LDS, 16B per lane; LDS dest = wave-uniform base + lane*16
  __builtin_amdgcn_global_load_lds((AS1 const void*)g, (AS3 void*)l, 16, 0, 0);
}

__device__ inline f32x4 mfma16(s16x8 a, s16x8 b, f32x4 c) {
  return __builtin_amdgcn_mfma_f32_16x16x32_bf16(
      __builtin_bit_cast(bf16x8, a), __builtin_bit_cast(bf16x8, b), c, 0, 0, 0);
}

__device__ inline short f2bf(float f) {  // RNE float->bf16 bits
  unsigned u = __builtin_bit_cast(unsigned, f);
  u += 0x7FFFu + ((u >> 16) & 1u);
  return (short)(u >> 16);
}
__device__ inline float bf2f(short x) {
  unsigned u = ((unsigned)(unsigned short)x) << 16;
  return __builtin_bit_cast(float, u);
}

// ---------- cast f32 -> bf16 ----------
__global__ void cast_bf(const float* __restrict__ in, short* __restrict__ out, int n4) {
  int i = blockIdx.x * 256 + threadIdx.x;
  if (i < n4) {
    f32x4 v = *(const f32x4*)(in + (size_t)i * 4);
    s16x4 o;
#pragma unroll
    for (int r = 0; r < 4; ++r) o[r] = f2bf(v[r]);
    *(s16x4*)(out + (size_t)i * 4) = o;
  }
}

// ---------- GEMM: C[M][N] = A[M][K](bf16) * B[N][K](bf16)^T + bias[N] ----------
// 128x128 tile, BK=32, 4 waves (2x2 of 64x64), m97 structure.
template <int OBF>
__global__ __launch_bounds__(256, 2) void gemm_bt(
    const short* __restrict__ A, const short* __restrict__ B,
    const float* __restrict__ bias, void* __restrict__ Cv,
    int M, int N, int K) {
  const int tid = threadIdx.x, w = tid >> 6, lane = tid & 63;
  const int quad = lane >> 4, l15 = lane & 15;
  const int wm = w >> 1, wn = w & 1;
  const int m0 = blockIdx.y * 128, n0 = blockIdx.x * 128;
  __shared__ short As[128 * 32], Bs[128 * 32];
  f32x4 acc[4][4];
#pragma unroll
  for (int i = 0; i < 4; ++i)
#pragma unroll
    for (int j = 0; j < 4; ++j) acc[i][j] = (f32x4){0.f, 0.f, 0.f, 0.f};
  const int rs = lane >> 2, cs = (lane & 3) * 8;
  const int nkt = K >> 5;
  for (int kt = 0; kt < nkt; ++kt) {
    const int k0 = kt * 32;
#pragma unroll
    for (int j = 0; j < 2; ++j) {
      gload16(A + (size_t)(m0 + w * 32 + j * 16 + rs) * K + k0 + cs, &As[w * 1024 + j * 512]);
      gload16(B + (size_t)(n0 + w * 32 + j * 16 + rs) * K + k0 + cs, &Bs[w * 1024 + j * 512]);
    }
    __syncthreads();
    s16x8 af[4], bfr[4];
#pragma unroll
    for (int i = 0; i < 4; ++i) {
      af[i]  = *(const s16x8*)&As[(wm * 64 + i * 16 + l15) * 32 + quad * 8];
      bfr[i] = *(const s16x8*)&Bs[(wn * 64 + i * 16 + l15) * 32 + quad * 8];
    }
#pragma unroll
    for (int ms = 0; ms < 4; ++ms)
#pragma unroll
      for (int ns = 0; ns < 4; ++ns)
        acc[ms][ns] = mfma16(af[ms], bfr[ns], acc[ms][ns]);
    __syncthreads();
  }
#pragma unroll
  for (int ms = 0; ms < 4; ++ms) {
    const int row0 = m0 + wm * 64 + ms * 16 + quad * 4;
#pragma unroll
    for (int ns = 0; ns < 4; ++ns) {
      const int col = n0 + wn * 64 + ns * 16 + l15;
      const float bv = bias[col];
#pragma unroll
      for (int r = 0; r < 4; ++r) {
        float v = acc[ms][ns][r] + bv;
        if (OBF) ((short*)Cv)[(size_t)(row0 + r) * N + col] = f2bf(v);
        else     ((float*)Cv)[(size_t)(row0 + r) * N + col] = v;
      }
    }
  }
}

// ---------- repack qkv[t][r] -> qh/kh [bh][s][d] (q scaled 1/8) ----------
__global__ void repack_qk(const short* __restrict__ qkv,
                          short* __restrict__ qh, short* __restrict__ kh) {
  int idx = blockIdx.x * 256 + threadIdx.x;  // over 64*1024*2*16 chunks of 4 shorts
  int dg = idx & 15;
  int ty = (idx >> 4) & 1;
  int s  = (idx >> 5) & 1023;
  int bh = idx >> 15;
  int b_ = bh >> 4, h_ = bh & 15;
  const short* src = qkv + (size_t)(s * 4 + b_) * 3072 + h_ * 192 + ty * 64 + dg * 4;
  s16x4 v = *(const s16x4*)src;
  if (ty == 0) {
#pragma unroll
    for (int i = 0; i < 4; ++i) v[i] = f2bf(bf2f(v[i]) * 0.125f);
    *(s16x4*)&qh[((size_t)bh << 16) + s * 64 + dg * 4] = v;
  } else {
    *(s16x4*)&kh[((size_t)bh << 16) + s * 64 + dg * 4] = v;
  }
}

// ---------- v transpose: qkv[t][h*192+128+d] -> vT[bh][d][s] ----------
__global__ void transpose_v(const short* __restrict__ qkv, short* __restrict__ vT) {
  __shared__ short t[64][80];  // pad to 80 shorts (160B, 16B-aligned rows)
  int bh = blockIdx.x, st_ = blockIdx.y;
  int b_ = bh >> 4, h_ = bh & 15;
  int tid = threadIdx.x;
#pragma unroll
  for (int p = 0; p < 2; ++p) {
    int s_l = p * 32 + (tid >> 3), ch = tid & 7;
    const short* src = qkv + (size_t)((st_ * 64 + s_l) * 4 + b_) * 3072 + h_ * 192 + 128 + ch * 8;
    *(s16x8*)&t[s_l][ch * 8] = *(const s16x8*)src;
  }
  __syncthreads();
#pragma unroll
  for (int p = 0; p < 2; ++p) {
    int d_l = p * 32 + (tid >> 3), sc = tid & 7;
    s16x8 vv;
#pragma unroll
    for (int j = 0; j < 8; ++j) vv[j] = t[sc * 8 + j][d_l];
    *(s16x8*)&vT[((size_t)bh << 16) + d_l * 1024 + st_ * 64 + sc * 8] = vv;
  }
}

// ---------- fused flash attention with softmax_1, bias add/mul, key mask ----------
// grid (64 bh, 8 q-tiles), 256 thr = 4 waves, each wave 32 q; k-tiles of 32.
__global__ __launch_bounds__(256, 2) void attn_fused(
    const short* __restrict__ qh, const short* __restrict__ kh,
    const short* __restrict__ vT, const float* __restrict__ bias,
    const float* __restrict__ abm, const int* __restrict__ kpm,
    short* __restrict__ attnbf) {
  const int tid = threadIdx.x;
  const int w = tid >> 6, lane = tid & 63, quad = lane >> 4, l15 = lane & 15;
  const int bh = blockIdx.x, qb = blockIdx.y;
  const int b_ = bh >> 4, h_ = bh & 15;
  const short* qhd = qh + ((size_t)bh << 16);
  const short* khd = kh + ((size_t)bh << 16);
  const short* vTd = vT + ((size_t)bh << 16);
  const float* biasd = bias + ((size_t)bh << 20);
  const float* abmd  = abm  + ((size_t)bh << 20);
  const int*   kpmd  = kpm + (b_ << 10);
  const int qw = qb * 128 + w * 32;

  __shared__ short kbuf[2][32 * 64];   // [k][d]
  __shared__ short vbuf[2][64 * 32];   // [d][k]
  __shared__ short wl[4][32 * 40];     // per-wave P tile [q][k], pad 40
  __shared__ float alds[4][32];        // per-wave per-q broadcast

  s16x8 qf[2][2];  // B-operand frags of Q^T: [q-sub][d-step]
#pragma unroll
  for (int ns = 0; ns < 2; ++ns)
#pragma unroll
    for (int t = 0; t < 2; ++t)
      qf[ns][t] = *(const s16x8*)&qhd[(size_t)(qw + ns * 16 + l15) * 64 + t * 32 + quad * 8];

  f32x4 o[2][4];
#pragma unroll
  for (int ns = 0; ns < 2; ++ns)
#pragma unroll
    for (int ds = 0; ds < 4; ++ds) o[ns][ds] = (f32x4){0.f, 0.f, 0.f, 0.f};
  float mrun[2] = {-1e30f, -1e30f}, lrun[2] = {0.f, 0.f};

  struct Pack { f32x4 bs[2][2]; f32x4 ab[2][2]; i32x4 kp[2]; };
  Pack P0, P1;

  auto stage = [&](int kt, int pb) {
    gload16(khd + (size_t)kt * 2048 + w * 512 + lane * 8, &kbuf[pb][w * 512]);
    gload16(vTd + (size_t)(w * 16 + (lane >> 2)) * 1024 + kt * 32 + (lane & 3) * 8,
            &vbuf[pb][w * 512]);
  };
  auto loadP = [&](int kt, Pack& P) {
    const int kb = kt * 32;
#pragma unroll
    for (int ns = 0; ns < 2; ++ns) {
      const size_t qrow = (size_t)(qw + ns * 16 + l15) * 1024;
#pragma unroll
      for (int ms = 0; ms < 2; ++ms) {
        P.bs[ns][ms] = *(const f32x4*)&biasd[qrow + kb + ms * 16 + quad * 4];
        P.ab[ns][ms] = *(const f32x4*)&abmd [qrow + kb + ms * 16 + quad * 4];
      }
    }
#pragma unroll
    for (int ms = 0; ms < 2; ++ms)
      P.kp[ms] = *(const i32x4*)&kpmd[kb + ms * 16 + quad * 4];
  };

  auto compute = [&](int pb, Pack& P) {
    const f32x4 z4 = {0.f, 0.f, 0.f, 0.f};
    f32x4 st[2][2];  // S^T frags: rows=k (quad*4+reg), cols=q (l15)
#pragma unroll
    for (int ms = 0; ms < 2; ++ms) {
      s16x8 a0 = *(const s16x8*)&kbuf[pb][(ms * 16 + l15) * 64 + quad * 8];
      s16x8 a1 = *(const s16x8*)&kbuf[pb][(ms * 16 + l15) * 64 + 32 + quad * 8];
#pragma unroll
      for (int ns = 0; ns < 2; ++ns)
        st[ms][ns] = mfma16(a1, qf[ns][1], mfma16(a0, qf[ns][0], z4));
    }
    float mloc[2] = {-1e30f, -1e30f};
#pragma unroll
    for (int ms = 0; ms < 2; ++ms)
#pragma unroll
      for (int ns = 0; ns < 2; ++ns)
#pragma unroll
        for (int r = 0; r < 4; ++r) {
          float sc = st[ms][ns][r] + P.bs[ns][ms][r];
          sc = (P.kp[ms][r] != 0) ? -1e30f : sc;
          st[ms][ns][r] = sc;
          mloc[ns] = fmaxf(mloc[ns], sc);
        }
    float al[2], lloc[2] = {0.f, 0.f};
#pragma unroll
    for (int ns = 0; ns < 2; ++ns) {
      mloc[ns] = fmaxf(mloc[ns], __shfl_xor(mloc[ns], 16));
      mloc[ns] = fmaxf(mloc[ns], __shfl_xor(mloc[ns], 32));
      float mn = fmaxf(mrun[ns], mloc[ns]);
      al[ns] = __expf(mrun[ns] - mn);
      mrun[ns] = mn;
    }
#pragma unroll
    for (int ms = 0; ms < 2; ++ms)
#pragma unroll
      for (int ns = 0; ns < 2; ++ns)
#pragma unroll
        for (int r = 0; r < 4; ++r) {
          // force e=0 on masked keys (also guards the all-masked-tile m=-1e30 corner)
          float e = (P.kp[ms][r] != 0) ? 0.f : __expf(st[ms][ns][r] - mrun[ns]);
          st[ms][ns][r] = e;
          lloc[ns] += e;
        }
#pragma unroll
    for (int ns = 0; ns < 2; ++ns) {
      lloc[ns] += __shfl_xor(lloc[ns], 16);
      lloc[ns] += __shfl_xor(lloc[ns], 32);
      lrun[ns] = lrun[ns] * al[ns] + lloc[ns];
      alds[w][ns * 16 + l15] = al[ns];  // all quads write identical value
    }
#pragma unroll
    for (int ms = 0; ms < 2; ++ms)
#pragma unroll
      for (int ns = 0; ns < 2; ++ns) {
        s16x4 pk;
#pragma unroll
        for (int r = 0; r < 4; ++r) pk[r] = f2bf(st[ms][ns][r] * P.ab[ns][ms][r]);
        *(s16x4*)&wl[w][(ns * 16 + l15) * 40 + ms * 16 + quad * 4] = pk;
      }
    f32x4 av[2];
    s16x8 pf[2];
#pragma unroll
    for (int ns = 0; ns < 2; ++ns) {
      av[ns] = *(const f32x4*)&alds[w][ns * 16 + quad * 4];
      pf[ns] = *(const s16x8*)&wl[w][(ns * 16 + l15) * 40 + quad * 8];
    }
#pragma unroll
    for (int ns = 0; ns < 2; ++ns)
#pragma unroll
      for (int ds = 0; ds < 4; ++ds) o[ns][ds] *= av[ns];
#pragma unroll
    for (int ds = 0; ds < 4; ++ds) {
      s16x8 vf = *(const s16x8*)&vbuf[pb][(ds * 16 + l15) * 32 + quad * 8];
#pragma unroll
      for (int ns = 0; ns < 2; ++ns) o[ns][ds] = mfma16(pf[ns], vf, o[ns][ds]);
    }
  };

  stage(0, 0);
  loadP(0, P0);
  __syncthreads();
  for (int kt = 0; kt < 32; kt += 2) {
    stage(kt + 1, 1);
    loadP(kt + 1, P1);
    compute(0, P0);
    __syncthreads();
    if (kt + 2 < 32) { stage(kt + 2, 0); loadP(kt + 2, P0); }
    compute(1, P1);
    __syncthreads();
  }

#pragma unroll
  for (int ns = 0; ns < 2; ++ns) {
    float rd = 1.f / (__expf(-mrun[ns]) + lrun[ns]);  // softmax_1 denominator
    alds[w][ns * 16 + l15] = rd;
  }
  f32x4 rdv[2];
#pragma unroll
  for (int ns = 0; ns < 2; ++ns) rdv[ns] = *(const f32x4*)&alds[w][ns * 16 + quad * 4];
#pragma unroll
  for (int ns = 0; ns < 2; ++ns)
#pragma unroll
    for (int ds = 0; ds < 4; ++ds) {
      f32x4 ov = o[ns][ds] * rdv[ns];
#pragma unroll
      for (int r = 0; r < 4; ++r) {
        int s = qw + ns * 16 + quad * 4 + r;
        attnbf[(size_t)(s * 4 + b_) * 1024 + h_ * 64 + ds * 16 + l15] = f2bf(ov[r]);
      }
    }
}

// ---------- launcher ----------
extern "C" void kernel_launch(void* const* d_in, const int* in_sizes, int n_in,
                              void* d_out, int out_size, void* d_ws, size_t ws_size,
                              hipStream_t stream) {
  const float* x     = (const float*)d_in[0];
  const float* bias  = (const float*)d_in[1];
  const float* abm   = (const float*)d_in[2];
  const int*   kpm   = (const int*)  d_in[3];
  const float* W_in  = (const float*)d_in[4];
  const float* b_in  = (const float*)d_in[5];
  const float* W_out = (const float*)d_in[6];
  const float* b_out = (const float*)d_in[7];
  float* out = (float*)d_out;

  char* ws = (char*)d_ws;
  short* xbf    = (short*)(ws);                 // 8 MB
  short* wibf   = (short*)(ws + (8u << 20));    // 6 MB
  short* wobf   = (short*)(ws + (14u << 20) + (512u << 10)); // 2 MB
  short* qkvbf  = (short*)(ws + (16u << 20) + (768u << 10)); // 24 MB
  short* qh     = (short*)(ws + (40u << 20) + (768u << 10)); // 8 MB
  short* kh     = (short*)(ws + (48u << 20) + (768u << 10)); // 8 MB
  short* vTh    = (short*)(ws + (56u << 20) + (768u << 10)); // 8 MB
  short* attnbf = (short*)(ws + (64u << 20) + (768u << 10)); // 8 MB

  cast_bf<<<4096, 256, 0, stream>>>(x, xbf, 1048576);
  cast_bf<<<3072, 256, 0, stream>>>(W_in, wibf, 786432);
  cast_bf<<<1024, 256, 0, stream>>>(W_out, wobf, 262144);

  gemm_bt<1><<<dim3(24, 32), 256, 0, stream>>>(xbf, wibf, b_in, (void*)qkvbf, 4096, 3072, 1024);
  // note: gemm_bt<1> writes f32 -- we need bf16 for qkv; use OBF=1? No: OBF template:
  // OBF=1 -> bf16 out. (template param meaning: OBF nonzero = bf16 output)

  repack_qk<<<8192, 256, 0, stream>>>(qkvbf, qh, kh);
  transpose_v<<<dim3(64, 16), 256, 0, stream>>>(qkvbf, vTh);

  attn_fused<<<dim3(64, 8), 256, 0, stream>>>(qh, kh, vTh, bias, abm, kpm, attnbf);

  gemm_bt<0><<<dim3(8, 32), 256, 0, stream>>>(attnbf, wobf, b_out, (void*)out, 4096, 1024, 1024);
}

// Round 2
// 627.317 us; speedup vs baseline: 1.0230x; 1.0230x over previous
//
#include <hip/hip_runtime.h>
#include <stdint.h>
#include <stddef.h>

// ---------- types ----------
typedef __attribute__((ext_vector_type(4))) float f32x4;
typedef __attribute__((ext_vector_type(4))) int   i32x4;
typedef __attribute__((ext_vector_type(8))) short s16x8;
typedef __attribute__((ext_vector_type(4))) short s16x4;
typedef __attribute__((ext_vector_type(8))) __bf16 bf16x8;

#define AS3 __attribute__((address_space(3)))
#define AS1 __attribute__((address_space(1)))

__device__ inline void gload16(const void* g, void* l) {
  // async global->LDS, 16B per lane; LDS dest = wave-uniform base + lane*16
  __builtin_amdgcn_global_load_lds((AS1 const void*)g, (AS3 void*)l, 16, 0, 0);
}

__device__ inline f32x4 mfma16(s16x8 a, s16x8 b, f32x4 c) {
  return __builtin_amdgcn_mfma_f32_16x16x32_bf16(
      __builtin_bit_cast(bf16x8, a), __builtin_bit_cast(bf16x8, b), c, 0, 0, 0);
}

__device__ inline short f2bf(float f) {  // RNE float->bf16 bits
  unsigned u = __builtin_bit_cast(unsigned, f);
  u += 0x7FFFu + ((u >> 16) & 1u);
  return (short)(u >> 16);
}
__device__ inline float bf2f(short x) {
  unsigned u = ((unsigned)(unsigned short)x) << 16;
  return __builtin_bit_cast(float, u);
}

// ---------- fused cast f32 -> bf16 of x, W_in, W_out (one launch) ----------
// ranges in f32x4 units: x 1048576 | W_in 786432 | W_out 262144  (total 2097152)
__global__ void cast_all(const float* __restrict__ x, const float* __restrict__ wi,
                         const float* __restrict__ wo, short* __restrict__ xb,
                         short* __restrict__ wib, short* __restrict__ wob) {
  int i = blockIdx.x * 256 + threadIdx.x;
  const float* src;
  short* dst;
  int off;
  if (i < 1048576)      { src = x;  dst = xb;  off = i; }
  else if (i < 1835008) { src = wi; dst = wib; off = i - 1048576; }
  else                  { src = wo; dst = wob; off = i - 1835008; }
  f32x4 v = *(const f32x4*)(src + (size_t)off * 4);
  s16x4 o;
#pragma unroll
  for (int r = 0; r < 4; ++r) o[r] = f2bf(v[r]);
  *(s16x4*)(dst + (size_t)off * 4) = o;
}

// ---------- GEMM: C[M][N] = A[M][K](bf16) * B[N][K](bf16)^T + bias[N] ----------
// FR=4: 128x128 tile (4 waves as 2x2 of 64x64). FR=2: 64x64 tile (2x2 of 32x32).
template <int OBF, int FR>
__global__ __launch_bounds__(256, 2) void gemm_bt(
    const short* __restrict__ A, const short* __restrict__ B,
    const float* __restrict__ bias, void* __restrict__ Cv,
    int M, int N, int K) {
  const int TILE = FR * 32;
  const int tid = threadIdx.x, w = tid >> 6, lane = tid & 63;
  const int quad = lane >> 4, l15 = lane & 15;
  const int wm = w >> 1, wn = w & 1;
  const int m0 = blockIdx.y * TILE, n0 = blockIdx.x * TILE;
  __shared__ short As[TILE * 32], Bs[TILE * 32];
  f32x4 acc[FR][FR];
#pragma unroll
  for (int i = 0; i < FR; ++i)
#pragma unroll
    for (int j = 0; j < FR; ++j) acc[i][j] = (f32x4){0.f, 0.f, 0.f, 0.f};
  const int rs = lane >> 2, cs = (lane & 3) * 8;
  const int nkt = K >> 5;
  for (int kt = 0; kt < nkt; ++kt) {
    const int k0 = kt * 32;
#pragma unroll
    for (int j = 0; j < FR / 2; ++j) {
      gload16(A + (size_t)(m0 + w * (FR * 8) + j * 16 + rs) * K + k0 + cs,
              &As[w * (FR * 256) + j * 512]);
      gload16(B + (size_t)(n0 + w * (FR * 8) + j * 16 + rs) * K + k0 + cs,
              &Bs[w * (FR * 256) + j * 512]);
    }
    __syncthreads();
    s16x8 af[FR], bfr[FR];
#pragma unroll
    for (int i = 0; i < FR; ++i) {
      af[i]  = *(const s16x8*)&As[(wm * (FR * 16) + i * 16 + l15) * 32 + quad * 8];
      bfr[i] = *(const s16x8*)&Bs[(wn * (FR * 16) + i * 16 + l15) * 32 + quad * 8];
    }
#pragma unroll
    for (int ms = 0; ms < FR; ++ms)
#pragma unroll
      for (int ns = 0; ns < FR; ++ns)
        acc[ms][ns] = mfma16(af[ms], bfr[ns], acc[ms][ns]);
    __syncthreads();
  }
#pragma unroll
  for (int ms = 0; ms < FR; ++ms) {
    const int row0 = m0 + wm * (FR * 16) + ms * 16 + quad * 4;
#pragma unroll
    for (int ns = 0; ns < FR; ++ns) {
      const int col = n0 + wn * (FR * 16) + ns * 16 + l15;
      const float bv = bias[col];
#pragma unroll
      for (int r = 0; r < 4; ++r) {
        float v = acc[ms][ns][r] + bv;
        if (OBF) ((short*)Cv)[(size_t)(row0 + r) * N + col] = f2bf(v);
        else     ((float*)Cv)[(size_t)(row0 + r) * N + col] = v;
      }
    }
  }
}

// ---------- fused repack: qkv -> qh [bh][s][d] (x1/8), kh [bh][s][d], vT [bh][d][s]
// grid (64 bh, 16 s-tiles of 64), 256 threads
__global__ void repack_all(const short* __restrict__ qkv, short* __restrict__ qh,
                           short* __restrict__ kh, short* __restrict__ vT) {
  __shared__ short t[64][80];  // v tile [s][d], pad 80 shorts (160B rows, 16B-mult)
  const int bh = blockIdx.x, st_ = blockIdx.y;
  const int b_ = bh >> 4, h_ = bh & 15;
  const int tid = threadIdx.x;
  // q/k: 64 s x 2 types x 8 chunks = 1024 chunks of 8 shorts
#pragma unroll
  for (int part = 0; part < 4; ++part) {
    int lin = part * 256 + tid;
    int dg = lin & 7, ty = (lin >> 3) & 1, s_l = lin >> 4;
    int s = st_ * 64 + s_l;
    s16x8 v = *(const s16x8*)(qkv + (size_t)(s * 4 + b_) * 3072 + h_ * 192 + ty * 64 + dg * 8);
    if (ty == 0) {
#pragma unroll
      for (int i = 0; i < 8; ++i) v[i] = f2bf(bf2f(v[i]) * 0.125f);
      *(s16x8*)&qh[((size_t)bh << 16) + (size_t)s * 64 + dg * 8] = v;
    } else {
      *(s16x8*)&kh[((size_t)bh << 16) + (size_t)s * 64 + dg * 8] = v;
    }
  }
  // v load: 64 s x 8 chunks = 512 chunks
#pragma unroll
  for (int part = 0; part < 2; ++part) {
    int lin = part * 256 + tid;
    int ch = lin & 7, s_l = lin >> 3;
    int s = st_ * 64 + s_l;
    *(s16x8*)&t[s_l][ch * 8] =
        *(const s16x8*)(qkv + (size_t)(s * 4 + b_) * 3072 + h_ * 192 + 128 + ch * 8);
  }
  __syncthreads();
  // v transpose out: 64 d x 8 s-chunks = 512 chunks
#pragma unroll
  for (int part = 0; part < 2; ++part) {
    int lin = part * 256 + tid;
    int sc = lin & 7, d_l = lin >> 3;
    s16x8 vv;
#pragma unroll
    for (int j = 0; j < 8; ++j) vv[j] = t[sc * 8 + j][d_l];
    *(s16x8*)&vT[((size_t)bh << 16) + (size_t)d_l * 1024 + st_ * 64 + sc * 8] = vv;
  }
}

// ---------- fused flash attention with softmax_1, bias add/mul, key mask ----------
// grid (64 bh, 16 q-tiles of 64), 256 thr = 4 waves, each wave 16 q; k-tiles of 32.
__global__ __launch_bounds__(256, 4) void attn_fused(
    const short* __restrict__ qh, const short* __restrict__ kh,
    const short* __restrict__ vT, const float* __restrict__ bias,
    const float* __restrict__ abm, const int* __restrict__ kpm,
    short* __restrict__ attnbf) {
  const int tid = threadIdx.x;
  const int w = tid >> 6, lane = tid & 63, quad = lane >> 4, l15 = lane & 15;
  const int bh = blockIdx.x, qb = blockIdx.y;
  const int b_ = bh >> 4, h_ = bh & 15;
  const short* qhd = qh + ((size_t)bh << 16);
  const short* khd = kh + ((size_t)bh << 16);
  const short* vTd = vT + ((size_t)bh << 16);
  const float* biasd = bias + ((size_t)bh << 20);
  const float* abmd  = abm  + ((size_t)bh << 20);
  const int*   kpmd  = kpm + (b_ << 10);
  const int qw = qb * 64 + w * 16;

  __shared__ short kbuf[2][32 * 64];   // [k][d]
  __shared__ short vbuf[2][64 * 32];   // [d][k]
  __shared__ short wl[4][16 * 40];     // per-wave P tile [q][k], pad 40
  __shared__ float alds[4][16];        // per-wave per-q broadcast

  s16x8 qf[2];  // B-operand frags of Q^T (16 q rows), d-halves
#pragma unroll
  for (int t = 0; t < 2; ++t)
    qf[t] = *(const s16x8*)&qhd[(size_t)(qw + l15) * 64 + t * 32 + quad * 8];

  f32x4 o[4];
#pragma unroll
  for (int ds = 0; ds < 4; ++ds) o[ds] = (f32x4){0.f, 0.f, 0.f, 0.f};
  float mrun = -1e30f, lrun = 0.f;

  struct Pack { f32x4 bs[2]; f32x4 ab[2]; i32x4 kp[2]; };
  Pack P0, P1;

  auto stage = [&](int kt, int pb) {
    gload16(khd + (size_t)kt * 2048 + w * 512 + lane * 8, &kbuf[pb][w * 512]);
    gload16(vTd + (size_t)(w * 16 + (lane >> 2)) * 1024 + kt * 32 + (lane & 3) * 8,
            &vbuf[pb][w * 512]);
  };
  auto loadP = [&](int kt, Pack& P) {
    const int kb = kt * 32;
    const size_t qrow = (size_t)(qw + l15) * 1024;
#pragma unroll
    for (int ms = 0; ms < 2; ++ms) {
      P.bs[ms] = *(const f32x4*)&biasd[qrow + kb + ms * 16 + quad * 4];
      P.ab[ms] = *(const f32x4*)&abmd [qrow + kb + ms * 16 + quad * 4];
      P.kp[ms] = *(const i32x4*)&kpmd[kb + ms * 16 + quad * 4];
    }
  };

  auto compute = [&](int pb, Pack& P) {
    const f32x4 z4 = {0.f, 0.f, 0.f, 0.f};
    f32x4 st[2];  // S^T frags: rows=k (ms*16+quad*4+r), cols=q (l15)
#pragma unroll
    for (int ms = 0; ms < 2; ++ms) {
      s16x8 a0 = *(const s16x8*)&kbuf[pb][(ms * 16 + l15) * 64 + quad * 8];
      s16x8 a1 = *(const s16x8*)&kbuf[pb][(ms * 16 + l15) * 64 + 32 + quad * 8];
      st[ms] = mfma16(a1, qf[1], mfma16(a0, qf[0], z4));
    }
    float mloc = -1e30f;
#pragma unroll
    for (int ms = 0; ms < 2; ++ms)
#pragma unroll
      for (int r = 0; r < 4; ++r) {
        float sc = st[ms][r] + P.bs[ms][r];
        sc = (P.kp[ms][r] != 0) ? -1e30f : sc;
        st[ms][r] = sc;
        mloc = fmaxf(mloc, sc);
      }
    mloc = fmaxf(mloc, __shfl_xor(mloc, 16));
    mloc = fmaxf(mloc, __shfl_xor(mloc, 32));
    float mn = fmaxf(mrun, mloc);
    float al = __expf(mrun - mn);
    mrun = mn;
    float lloc = 0.f;
#pragma unroll
    for (int ms = 0; ms < 2; ++ms)
#pragma unroll
      for (int r = 0; r < 4; ++r) {
        // force e=0 on masked keys (guards all-masked-tile m=-1e30 corner too)
        float e = (P.kp[ms][r] != 0) ? 0.f : __expf(st[ms][r] - mrun);
        st[ms][r] = e;
        lloc += e;
      }
    lloc += __shfl_xor(lloc, 16);
    lloc += __shfl_xor(lloc, 32);
    lrun = lrun * al + lloc;
    alds[w][l15] = al;  // all quads write identical value
#pragma unroll
    for (int ms = 0; ms < 2; ++ms) {
      s16x4 pk;
#pragma unroll
      for (int r = 0; r < 4; ++r) pk[r] = f2bf(st[ms][r] * P.ab[ms][r]);
      *(s16x4*)&wl[w][l15 * 40 + ms * 16 + quad * 4] = pk;
    }
    f32x4 av = *(const f32x4*)&alds[w][quad * 4];
    s16x8 pf = *(const s16x8*)&wl[w][l15 * 40 + quad * 8];
#pragma unroll
    for (int ds = 0; ds < 4; ++ds) o[ds] *= av;
#pragma unroll
    for (int ds = 0; ds < 4; ++ds) {
      s16x8 vf = *(const s16x8*)&vbuf[pb][(ds * 16 + l15) * 32 + quad * 8];
      o[ds] = mfma16(pf, vf, o[ds]);
    }
  };

  stage(0, 0);
  loadP(0, P0);
  __syncthreads();
  for (int kt = 0; kt < 32; kt += 2) {
    stage(kt + 1, 1);
    loadP(kt + 1, P1);
    compute(0, P0);
    __syncthreads();
    if (kt + 2 < 32) { stage(kt + 2, 0); loadP(kt + 2, P0); }
    compute(1, P1);
    __syncthreads();
  }

  float rd = 1.f / (__expf(-mrun) + lrun);  // softmax_1 denominator
  alds[w][l15] = rd;
  f32x4 rdv = *(const f32x4*)&alds[w][quad * 4];
#pragma unroll
  for (int ds = 0; ds < 4; ++ds) {
    f32x4 ov = o[ds] * rdv;
#pragma unroll
    for (int r = 0; r < 4; ++r) {
      int s = qw + quad * 4 + r;
      attnbf[(size_t)(s * 4 + b_) * 1024 + h_ * 64 + ds * 16 + l15] = f2bf(ov[r]);
    }
  }
}

// ---------- launcher ----------
extern "C" void kernel_launch(void* const* d_in, const int* in_sizes, int n_in,
                              void* d_out, int out_size, void* d_ws, size_t ws_size,
                              hipStream_t stream) {
  const float* x     = (const float*)d_in[0];
  const float* bias  = (const float*)d_in[1];
  const float* abm   = (const float*)d_in[2];
  const int*   kpm   = (const int*)  d_in[3];
  const float* W_in  = (const float*)d_in[4];
  const float* b_in  = (const float*)d_in[5];
  const float* W_out = (const float*)d_in[6];
  const float* b_out = (const float*)d_in[7];
  float* out = (float*)d_out;

  char* ws = (char*)d_ws;
  short* xbf    = (short*)(ws);                              // 8 MB
  short* wibf   = (short*)(ws + (8u << 20));                 // 6 MB
  short* wobf   = (short*)(ws + (14u << 20) + (512u << 10)); // 2 MB
  short* qkvbf  = (short*)(ws + (16u << 20) + (768u << 10)); // 24 MB
  short* qh     = (short*)(ws + (40u << 20) + (768u << 10)); // 8 MB
  short* kh     = (short*)(ws + (48u << 20) + (768u << 10)); // 8 MB
  short* vTh    = (short*)(ws + (56u << 20) + (768u << 10)); // 8 MB
  short* attnbf = (short*)(ws + (64u << 20) + (768u << 10)); // 8 MB

  cast_all<<<8192, 256, 0, stream>>>(x, W_in, W_out, xbf, wibf, wobf);

  // qkv = x @ W_in^T + b_in  -> bf16
  gemm_bt<1, 4><<<dim3(24, 32), 256, 0, stream>>>(xbf, wibf, b_in, (void*)qkvbf,
                                                  4096, 3072, 1024);

  repack_all<<<dim3(64, 16), 256, 0, stream>>>(qkvbf, qh, kh, vTh);

  attn_fused<<<dim3(64, 16), 256, 0, stream>>>(qh, kh, vTh, bias, abm, kpm, attnbf);

  // out = attn @ W_out^T + b_out -> f32 (64x64 tiles: 1024 blocks = 4/CU)
  gemm_bt<0, 2><<<dim3(16, 64), 256, 0, stream>>>(attnbf, wobf, b_out, (void*)out,
                                                  4096, 1024, 1024);
}